// Round 18
// baseline (57.070 us; speedup 1.0000x reference)
//
#include <hip/hip_runtime.h>

#define DEVFN __device__ __forceinline__

constexpr int B = 4, S = 2048, H = 4, DH = 16, D = 64, F = 256;
constexpr int T = B * S;        // 8192 tokens
constexpr int PAIRS = B * H;    // 16
constexpr int CPP = 72;         // chunk-blocks per pair = sum_{qb=0..15}(qb/2+1)
constexpr int NZ = PAIRS * CPP; // 1152 attention partial blocks
constexpr int PSTRIDE = 1280;   // floats: 128 m + 128 l + 128x16 bf16 acc
constexpr float LOG2E = 1.44269504f;

typedef __attribute__((ext_vector_type(8))) short s16x8;
typedef __attribute__((ext_vector_type(16))) float f32x16;

DEVFN float wave_sum(float v) {
#pragma unroll
    for (int mask = 32; mask >= 1; mask >>= 1)
        v += __shfl_xor(v, mask, 64);
    return v;
}

DEVFN unsigned short f2bf(float f) {
    unsigned b = __float_as_uint(f);
    return (unsigned short)((b + 0x8000u) >> 16);
}
DEVFN unsigned pack_bf2(float lo, float hi) {
    unsigned a = __float_as_uint(lo), b = __float_as_uint(hi);
    return ((a + 0x8000u) >> 16) | ((b + 0x8000u) & 0xffff0000u);
}
DEVFN unsigned cvtpk(float lo, float hi) {
    unsigned r;
    asm("v_cvt_pk_bf16_f32 %0, %1, %2" : "=v"(r) : "v"(lo), "v"(hi));
    return r;
}
DEVFN void plswap(unsigned& a, unsigned& b) {
#if __has_builtin(__builtin_amdgcn_permlane32_swap)
    typedef unsigned uv2 __attribute__((ext_vector_type(2)));
    uv2 r = __builtin_amdgcn_permlane32_swap(a, b, false, false);
    a = r[0]; b = r[1];
#else
    asm volatile("v_permlane32_swap_b32 %0, %1" : "+v"(a), "+v"(b));
#endif
}

// ---------------------------------------------------------------- kernel 1
// QKV projection, 32 tokens per block (256 thr, grid 256). x staged
// TRANSPOSED in LDS (padded, aligned) -> b128 broadcast reads; weight-load
// instruction count halved vs 8-token version. Blocks 0..15 also build
// fp32 row-quad packed weights wo4/w14/w24 for k_post.
__global__ __launch_bounds__(256) void k_qkv(
    const float* __restrict__ x,
    const float* __restrict__ wq, const float* __restrict__ bq,
    const float* __restrict__ wk, const float* __restrict__ bk,
    const float* __restrict__ wv, const float* __restrict__ bv,
    const float* __restrict__ wo, const float* __restrict__ w1,
    const float* __restrict__ w2,
    unsigned short* __restrict__ Qb, unsigned short* __restrict__ Kb,
    unsigned short* __restrict__ Vtg,
    float4* __restrict__ wo4, float4* __restrict__ w14,
    float4* __restrict__ w24)
{
    __shared__ float xst[64][36];    // transposed x tile, 144B row (aligned)
    int tid = threadIdx.x;
    int t0 = blockIdx.x * 32;

    // coalesced load of x, transposed store to LDS
    int token = tid >> 3, dseg = tid & 7;
    float4 xa = *(const float4*)(x + (size_t)(t0 + token) * D + dseg * 8);
    float4 xb = *(const float4*)(x + (size_t)(t0 + token) * D + dseg * 8 + 4);

    if (blockIdx.x < 16) {            // one-time packed weight build
        int bi = blockIdx.x;
        if (tid < 64) {               // wo4: 1024 = 16 d4 x 64 j
            int idx = bi * 64 + tid;
            int d4 = idx >> 6, j = idx & 63;
            float4 v = { wo[(4 * d4 + 0) * D + j], wo[(4 * d4 + 1) * D + j],
                         wo[(4 * d4 + 2) * D + j], wo[(4 * d4 + 3) * D + j] };
            wo4[idx] = v;
        }
        {                             // w14: 4096 = 16 d4 x 256 f
            int idx = bi * 256 + tid;
            int d4 = idx >> 8, f = idx & 255;
            float4 v = { w1[(4 * d4 + 0) * F + f], w1[(4 * d4 + 1) * F + f],
                         w1[(4 * d4 + 2) * F + f], w1[(4 * d4 + 3) * F + f] };
            w14[idx] = v;
        }
        {                             // w24: 4096 = 64 f4 x 64 j
            int idx = bi * 256 + tid;
            int f4 = idx >> 6, j = idx & 63;
            float4 v = { w2[(4 * f4 + 0) * D + j], w2[(4 * f4 + 1) * D + j],
                         w2[(4 * f4 + 2) * D + j], w2[(4 * f4 + 3) * D + j] };
            w24[idx] = v;
        }
    }

    xst[dseg * 8 + 0][token] = xa.x;
    xst[dseg * 8 + 1][token] = xa.y;
    xst[dseg * 8 + 2][token] = xa.z;
    xst[dseg * 8 + 3][token] = xa.w;
    xst[dseg * 8 + 4][token] = xb.x;
    xst[dseg * 8 + 5][token] = xb.y;
    xst[dseg * 8 + 6][token] = xb.z;
    xst[dseg * 8 + 7][token] = xb.w;
    __syncthreads();

    int j = tid & 63, g = tid >> 6;   // g in 0..3, 8 tokens each
    int h = j >> 4, k = j & 15;
    int wbase = h * (D * DH) + k;

    float qa[8], ka[8], va[8];
#pragma unroll
    for (int i = 0; i < 8; ++i) { qa[i] = bq[j]; ka[i] = bk[j]; va[i] = bv[j]; }

#pragma unroll 4
    for (int d = 0; d < D; ++d) {
        float wqv = wq[wbase + d * DH];
        float wkv = wk[wbase + d * DH];
        float wvv = wv[wbase + d * DH];
        float4 xv0 = *(const float4*)&xst[d][g * 8];
        float4 xv1 = *(const float4*)&xst[d][g * 8 + 4];
        float xe[8] = { xv0.x, xv0.y, xv0.z, xv0.w, xv1.x, xv1.y, xv1.z, xv1.w };
#pragma unroll
        for (int i = 0; i < 8; ++i) {
            qa[i] = fmaf(xe[i], wqv, qa[i]);
            ka[i] = fmaf(xe[i], wkv, ka[i]);
            va[i] = fmaf(xe[i], wvv, va[i]);
        }
    }
    int b = t0 >> 11;
    int pair = b * H + h;
    unsigned short vv[8];
#pragma unroll
    for (int i = 0; i < 8; ++i) {
        int t = t0 + g * 8 + i;
        int s = t & (S - 1);
        int off = (pair * S + s) * DH + k;
        Qb[off] = f2bf(qa[i] * (0.25f * LOG2E));
        Kb[off] = f2bf(ka[i]);
        vv[i] = f2bf(va[i]);
    }
    int s0 = (t0 & (S - 1)) + g * 8;
    uint4 pk;
    pk.x = (unsigned)vv[0] | ((unsigned)vv[1] << 16);
    pk.y = (unsigned)vv[2] | ((unsigned)vv[3] << 16);
    pk.z = (unsigned)vv[4] | ((unsigned)vv[5] << 16);
    pk.w = (unsigned)vv[6] | ((unsigned)vv[7] << 16);
    *(uint4*)(Vtg + (size_t)(pair * DH + k) * S + s0) = pk;
}

// ---------------------------------------------------------------- kernel 2
// MFMA flash attention partial (R10-R12 verbatim) + XCD-bijective block
// swizzle (1152 = 8 x 144): each XCD's L2 sees ~2 pairs' K/V.
__global__ __launch_bounds__(256) void k_attn_part(
    const unsigned short* __restrict__ Qb, const unsigned short* __restrict__ Kb,
    const unsigned short* __restrict__ Vtg, float* __restrict__ P)
{
    __shared__ unsigned short Kt[256][16];   // chunk16 slot ^= key&1
    __shared__ unsigned short Vt[16][264];   // padded rows

    int tid = threadIdx.x, lane = tid & 63, w = tid >> 6;

    int bid0 = blockIdx.x;
    int z = (bid0 & 7) * 144 + (bid0 >> 3);  // XCD-bijective swizzle
    int pair = z / CPP;
    int rem = z - pair * CPP;
    int qb = 0, cum = 0;
    while (cum + (qb >> 1) + 1 <= rem) { cum += (qb >> 1) + 1; ++qb; }
    int kc = rem - cum;
    int kbase = kc << 8;
    int qbase = qb << 7;

    {
        const uint4* src = (const uint4*)(Kb + (size_t)(pair * S + kbase + tid) * DH);
        uint4 lo = src[0], hi = src[1];
        *(uint4*)&Kt[tid][(tid & 1) * 8] = lo;
        *(uint4*)&Kt[tid][((tid & 1) ^ 1) * 8] = hi;
        int r = tid >> 4, cc = tid & 15;
        const uint4* vs = (const uint4*)(Vtg + (size_t)(pair * DH + r) * S + kbase + cc * 16);
        uint4 v0 = vs[0], v1 = vs[1];
        *(uint4*)&Vt[r][cc * 16] = v0;
        *(uint4*)&Vt[r][cc * 16 + 8] = v1;
    }
    __syncthreads();

    int qn = lane & 31, g = lane >> 5;
    int q0w = qbase + w * 32;
    int qg = q0w + qn;
    int vrow = lane & 15;

    s16x8 qf = *(const s16x8*)(Qb + (size_t)(pair * S + qg) * DH + g * 8);

    f32x16 czero;
#pragma unroll
    for (int i = 0; i < 16; ++i) czero[i] = 0.f;
    f32x16 acc = czero;
    float mrun = -1e30f, lsum = 0.f;

    int nt = ((q0w + 31 - kbase) >> 5) + 1;
    if (nt > 8) nt = 8;

    int krow0 = qn;
    s16x8 kf = *(const s16x8*)&Kt[krow0][(g ^ (krow0 & 1)) * 8];

    for (int t = 0; t < nt; ++t) {
        int kl = t * 32;
        s16x8 vf0 = *(const s16x8*)&Vt[vrow][kl + g * 8];
        s16x8 vf1 = *(const s16x8*)&Vt[vrow][kl + 16 + g * 8];
        int tn = (t + 1 < nt) ? (t + 1) : t;
        int krown = tn * 32 + qn;
        s16x8 kfn = *(const s16x8*)&Kt[krown][(g ^ (krown & 1)) * 8];

        f32x16 sc = __builtin_amdgcn_mfma_f32_32x32x16_bf16(kf, qf, czero, 0, 0, 0);
        if (t == nt - 1) {                        // diagonal tile: causal mask
            int qml = qg - (kbase + kl);
#pragma unroll
            for (int r = 0; r < 16; ++r) {
                int m = (r & 3) + 8 * (r >> 2) + 4 * g;
                sc[r] = (m <= qml) ? sc[r] : -1e30f;
            }
        }
        float t0a = fmaxf(fmaxf(sc[0], sc[1]), sc[2]);
        float t1a = fmaxf(fmaxf(sc[3], sc[4]), sc[5]);
        float t2a = fmaxf(fmaxf(sc[6], sc[7]), sc[8]);
        float t3a = fmaxf(fmaxf(sc[9], sc[10]), sc[11]);
        float t4a = fmaxf(fmaxf(sc[12], sc[13]), sc[14]);
        float tm = fmaxf(fmaxf(fmaxf(t0a, t1a), fmaxf(t2a, t3a)),
                         fmaxf(t4a, sc[15]));
        tm = fmaxf(tm, __shfl_xor(tm, 32, 64));
        float mnew = fmaxf(mrun, tm);
        float scale = exp2f(mrun - mnew);
        mrun = mnew;
        float p[16];
        float ts0 = 0.f, ts1 = 0.f, ts2 = 0.f, ts3 = 0.f;
#pragma unroll
        for (int r = 0; r < 16; r += 4) {
            p[r]     = exp2f(sc[r] - mnew);     ts0 += p[r];
            p[r + 1] = exp2f(sc[r + 1] - mnew); ts1 += p[r + 1];
            p[r + 2] = exp2f(sc[r + 2] - mnew); ts2 += p[r + 2];
            p[r + 3] = exp2f(sc[r + 3] - mnew); ts3 += p[r + 3];
        }
        float ts = (ts0 + ts1) + (ts2 + ts3);
        ts += __shfl_xor(ts, 32, 64);
        lsum = fmaf(lsum, scale, ts);
#pragma unroll
        for (int r = 0; r < 8; ++r) acc[r] *= scale;

        unsigned a0 = cvtpk(p[0],  p[1]);
        unsigned a1 = cvtpk(p[2],  p[3]);
        unsigned a2 = cvtpk(p[4],  p[5]);
        unsigned a3 = cvtpk(p[6],  p[7]);
        unsigned b0 = cvtpk(p[8],  p[9]);
        unsigned b1 = cvtpk(p[10], p[11]);
        unsigned b2 = cvtpk(p[12], p[13]);
        unsigned b3 = cvtpk(p[14], p[15]);
        plswap(a0, a2);
        plswap(a1, a3);
        plswap(b0, b2);
        plswap(b1, b3);
        union UU { unsigned u[4]; s16x8 v; };
        UU pf0, pf1;
        pf0.u[0] = a0; pf0.u[1] = a1; pf0.u[2] = a2; pf0.u[3] = a3;
        pf1.u[0] = b0; pf1.u[1] = b1; pf1.u[2] = b2; pf1.u[3] = b3;

        acc = __builtin_amdgcn_mfma_f32_32x32x16_bf16(vf0, pf0.v, acc, 0, 0, 0);
        acc = __builtin_amdgcn_mfma_f32_32x32x16_bf16(vf1, pf1.v, acc, 0, 0, 0);
        kf = kfn;
    }

    float* base = P + (size_t)z * PSTRIDE;
    if (lane < 32) {
        base[w * 32 + qn] = mrun;            // log2-domain max
        base[128 + w * 32 + qn] = lsum;
    }
    uint2 cA, cB;
    cA.x = pack_bf2(acc[0], acc[1]); cA.y = pack_bf2(acc[2], acc[3]);
    cB.x = pack_bf2(acc[4], acc[5]); cB.y = pack_bf2(acc[6], acc[7]);
    unsigned short* pa = (unsigned short*)(base + 256);
    *(uint2*)&pa[(w * 32 + qn) * 16 + 4 * g] = cA;
    *(uint2*)&pa[(w * 32 + qn) * 16 + 8 + 4 * g] = cB;
}

// ---------------------------------------------------------------- kernel 3
// Fused post (Round-11 60.78us version, verbatim): merge + oproj + LN1 +
// FFN + LN2. 16 tokens / 512 threads. fp32 row-quad weights.
__global__ __launch_bounds__(512) void k_post(
    const float* __restrict__ P, const float* __restrict__ x,
    const float4* __restrict__ wo4, const float* __restrict__ bo,
    const float* __restrict__ g1, const float* __restrict__ bb1,
    const float4* __restrict__ w14, const float* __restrict__ b1,
    const float4* __restrict__ w24, const float* __restrict__ b2,
    const float* __restrict__ g2, const float* __restrict__ bb2,
    float* __restrict__ out)
{
    __shared__ float As[16][68];     // merged attention out (head-concat)
    __shared__ float R1s[16][68];    // post-LN1
    __shared__ float hht[16][260];   // ffn hidden, token-major

    int tid = threadIdx.x;
    int t0 = blockIdx.x * 16;
    int b = t0 >> 11;
    int sbase = t0 & (S - 1);
    int qb = sbase >> 7;
    int nc = (qb >> 1) + 1;
    int cum = 0;
#pragma unroll
    for (int i = 0; i < 16; ++i) cum += (i < qb) ? ((i >> 1) + 1) : 0;

    // ---- phase 1: merge split-K partials (parallel prefetch) -> As
    {
        int pi = tid >> 3;           // 0..63 = (h, sl)
        int h = pi >> 4, sl = pi & 15;
        int dq = tid & 7;            // dims 2dq, 2dq+1
        int pair = b * H + h;
        int q = (sbase & 127) + sl;
        const float* base0 = P + ((size_t)pair * CPP + cum) * PSTRIDE;

        float mv[8], sv[8]; unsigned uv[8];
#pragma unroll
        for (int c = 0; c < 8; ++c) {
            int cc = (c < nc) ? c : (nc - 1);
            const float* bc = base0 + cc * PSTRIDE;
            float m_ = bc[q];
            float s_ = bc[128 + q];
            unsigned u_ = *(const unsigned*)((const unsigned short*)(bc + 256) + q * 16 + dq * 2);
            bool valid = (c < nc);
            mv[c] = valid ? m_ : -1e30f;
            sv[c] = valid ? s_ : 0.f;
            uv[c] = valid ? u_ : 0u;
        }
        float M = fmaxf(fmaxf(fmaxf(mv[0], mv[1]), fmaxf(mv[2], mv[3])),
                        fmaxf(fmaxf(mv[4], mv[5]), fmaxf(mv[6], mv[7])));
        float Sm = 0.f, a0 = 0.f, a1 = 0.f;
#pragma unroll
        for (int c = 0; c < 8; ++c) {
            float e = exp2f(mv[c] - M);
            Sm = fmaf(sv[c], e, Sm);
            a0 = fmaf(__uint_as_float(uv[c] << 16), e, a0);
            a1 = fmaf(__uint_as_float(uv[c] & 0xffff0000u), e, a1);
        }
        float inv = 1.f / Sm;
        float2 wv = { a0 * inv, a1 * inv };
        *(float2*)&As[sl][h * 16 + dq * 2] = wv;
    }
    __syncthreads();

    // ---- phase 2: out-proj + residual + LN1 -> R1s
    {
        int g = tid >> 6, j = tid & 63;      // tokens 2g, 2g+1
        float o0 = bo[j] + x[(t0 + 2 * g + 0) * D + j];
        float o1 = bo[j] + x[(t0 + 2 * g + 1) * D + j];
#pragma unroll
        for (int d4 = 0; d4 < 16; ++d4) {
            float4 wv = wo4[d4 * 64 + j];
            float4 a0v = *(const float4*)&As[2 * g + 0][4 * d4];
            float4 a1v = *(const float4*)&As[2 * g + 1][4 * d4];
            o0 = fmaf(a0v.x, wv.x, o0); o0 = fmaf(a0v.y, wv.y, o0);
            o0 = fmaf(a0v.z, wv.z, o0); o0 = fmaf(a0v.w, wv.w, o0);
            o1 = fmaf(a1v.x, wv.x, o1); o1 = fmaf(a1v.y, wv.y, o1);
            o1 = fmaf(a1v.z, wv.z, o1); o1 = fmaf(a1v.w, wv.w, o1);
        }
        float gj = g1[j], bj = bb1[j];
        {
            float mu = wave_sum(o0) * (1.f / 64.f);
            float dif = o0 - mu;
            float var = wave_sum(dif * dif) * (1.f / 64.f);
            R1s[2 * g + 0][j] = dif * rsqrtf(var + 1e-5f) * gj + bj;
        }
        {
            float mu = wave_sum(o1) * (1.f / 64.f);
            float dif = o1 - mu;
            float var = wave_sum(dif * dif) * (1.f / 64.f);
            R1s[2 * g + 1][j] = dif * rsqrtf(var + 1e-5f) * gj + bj;
        }
    }
    __syncthreads();

    // ---- phase 3: FFN stage 1 (hidden) -> hht (token-major)
    {
        int f = tid & 255, half = tid >> 8;
        float h[8];
#pragma unroll
        for (int t = 0; t < 8; ++t) h[t] = b1[f];
#pragma unroll
        for (int d4 = 0; d4 < 16; ++d4) {
            float4 wv = w14[d4 * 256 + f];
#pragma unroll
            for (int t = 0; t < 8; ++t) {
                float4 xv = *(const float4*)&R1s[half * 8 + t][4 * d4];
                h[t] = fmaf(xv.x, wv.x, h[t]); h[t] = fmaf(xv.y, wv.y, h[t]);
                h[t] = fmaf(xv.z, wv.z, h[t]); h[t] = fmaf(xv.w, wv.w, h[t]);
            }
        }
#pragma unroll
        for (int t = 0; t < 8; ++t)
            hht[half * 8 + t][f] = fmaxf(h[t], 0.f);
    }
    __syncthreads();

    // ---- phase 4: FFN stage 2 + residual + LN2 -> out
    {
        int g = tid >> 6, j = tid & 63;
        float y0 = b2[j] + R1s[2 * g + 0][j];
        float y1 = b2[j] + R1s[2 * g + 1][j];
#pragma unroll
        for (int f4 = 0; f4 < 64; ++f4) {
            float4 wv = w24[f4 * 64 + j];
            float4 h0 = *(const float4*)&hht[2 * g + 0][4 * f4];
            float4 h1 = *(const float4*)&hht[2 * g + 1][4 * f4];
            y0 = fmaf(h0.x, wv.x, y0); y0 = fmaf(h0.y, wv.y, y0);
            y0 = fmaf(h0.z, wv.z, y0); y0 = fmaf(h0.w, wv.w, y0);
            y1 = fmaf(h1.x, wv.x, y1); y1 = fmaf(h1.y, wv.y, y1);
            y1 = fmaf(h1.z, wv.z, y1); y1 = fmaf(h1.w, wv.w, y1);
        }
        float gj = g2[j], bj = bb2[j];
        {
            float mu = wave_sum(y0) * (1.f / 64.f);
            float dif = y0 - mu;
            float var = wave_sum(dif * dif) * (1.f / 64.f);
            out[(t0 + 2 * g + 0) * D + j] = dif * rsqrtf(var + 1e-5f) * gj + bj;
        }
        {
            float mu = wave_sum(y1) * (1.f / 64.f);
            float dif = y1 - mu;
            float var = wave_sum(dif * dif) * (1.f / 64.f);
            out[(t0 + 2 * g + 1) * D + j] = dif * rsqrtf(var + 1e-5f) * gj + bj;
        }
    }
}

// ----------------------------------------------------------------
extern "C" void kernel_launch(void* const* d_in, const int* in_sizes, int n_in,
                              void* d_out, int out_size, void* d_ws, size_t ws_size,
                              hipStream_t stream)
{
    const float* x   = (const float*)d_in[0];
    const float* wq  = (const float*)d_in[1];
    const float* bq  = (const float*)d_in[2];
    const float* wk  = (const float*)d_in[3];
    const float* bk  = (const float*)d_in[4];
    const float* wv  = (const float*)d_in[5];
    const float* bv  = (const float*)d_in[6];
    const float* wo  = (const float*)d_in[7];
    const float* bo  = (const float*)d_in[8];
    const float* g1  = (const float*)d_in[9];
    const float* be1 = (const float*)d_in[10];
    const float* w1  = (const float*)d_in[11];
    const float* b1  = (const float*)d_in[12];
    const float* w2  = (const float*)d_in[13];
    const float* b2  = (const float*)d_in[14];
    const float* g2  = (const float*)d_in[15];
    const float* be2 = (const float*)d_in[16];

    char* base = (char*)d_ws;
    unsigned short* Qb  = (unsigned short*)base;                  // 1 MB
    unsigned short* Kb  = (unsigned short*)(base + (1u << 20));   // 1 MB
    unsigned short* Vtg = (unsigned short*)(base + (2u << 20));   // 1 MB
    float*          P   = (float*)(base + (3u << 20));            // 5.9 MB
    float4*         wo4 = (float4*)(base + (9u << 20));           // 16 KB
    float4*         w14 = (float4*)(base + (9u << 20) + 0x10000); // 64 KB
    float4*         w24 = (float4*)(base + (9u << 20) + 0x20000); // 64 KB

    k_qkv      <<<T / 32, 256, 0, stream>>>(x, wq, bq, wk, bk, wv, bv,
                                            wo, w1, w2, Qb, Kb, Vtg,
                                            wo4, w14, w24);
    k_attn_part<<<NZ, 256, 0, stream>>>(Qb, Kb, Vtg, P);
    k_post     <<<T / 16, 512, 0, stream>>>(P, x, wo4, bo, g1, be1,
                                            w14, b1, w24, b2, g2, be2,
                                            (float*)d_out);
}

// Round 19
// 45.180 us; speedup vs baseline: 1.2632x; 1.2632x over previous
//
#include <hip/hip_runtime.h>

#define DEVFN __device__ __forceinline__

constexpr int B = 4, S = 2048, H = 4, DH = 16, D = 64, F = 256;
constexpr int T = B * S;        // 8192 tokens
constexpr int PAIRS = B * H;    // 16
constexpr int CPP = 72;         // chunk-blocks per pair = sum_{qb=0..15}(qb/2+1)
constexpr int NZ = PAIRS * CPP; // 1152 attention partial blocks
constexpr int PSTRIDE = 1280;   // floats: 128 m + 128 l + 128x16 bf16 acc
constexpr float LOG2E = 1.44269504f;

typedef __attribute__((ext_vector_type(8))) short s16x8;
typedef __attribute__((ext_vector_type(16))) float f32x16;
typedef __attribute__((ext_vector_type(4))) float f32x4;

DEVFN float wave_sum(float v) {
#pragma unroll
    for (int mask = 32; mask >= 1; mask >>= 1)
        v += __shfl_xor(v, mask, 64);
    return v;
}

DEVFN float bf2f(unsigned short u) { return __uint_as_float((unsigned)u << 16); }
DEVFN unsigned short f2bf(float f) {
    unsigned b = __float_as_uint(f);
    return (unsigned short)((b + 0x8000u) >> 16);
}
DEVFN unsigned pack_bf2(float lo, float hi) {
    unsigned a = __float_as_uint(lo), b = __float_as_uint(hi);
    return ((a + 0x8000u) >> 16) | ((b + 0x8000u) & 0xffff0000u);
}
DEVFN unsigned cvtpk(float lo, float hi) {
    unsigned r;
    asm("v_cvt_pk_bf16_f32 %0, %1, %2" : "=v"(r) : "v"(lo), "v"(hi));
    return r;
}
DEVFN void plswap(unsigned& a, unsigned& b) {
#if __has_builtin(__builtin_amdgcn_permlane32_swap)
    typedef unsigned uv2 __attribute__((ext_vector_type(2)));
    uv2 r = __builtin_amdgcn_permlane32_swap(a, b, false, false);
    a = r[0]; b = r[1];
#else
    asm volatile("v_permlane32_swap_b32 %0, %1" : "+v"(a), "+v"(b));
#endif
}

// ---------------------------------------------------------------- kernel 1
// QKV projection, 32 tokens per block (grid 256), transposed-x LDS (R18).
// Blocks 0..15 build bf16 MFMA-fragment weights wob/w1b/w2b for k_post:
// frag layout (16x16x32): lane l -> col = l&15, k = 8*(l>>4) + e.
__global__ __launch_bounds__(256) void k_qkv(
    const float* __restrict__ x,
    const float* __restrict__ wq, const float* __restrict__ bq,
    const float* __restrict__ wk, const float* __restrict__ bk,
    const float* __restrict__ wv, const float* __restrict__ bv,
    const float* __restrict__ wo, const float* __restrict__ w1,
    const float* __restrict__ w2,
    unsigned short* __restrict__ Qb, unsigned short* __restrict__ Kb,
    unsigned short* __restrict__ Vtg,
    unsigned* __restrict__ wob, unsigned* __restrict__ w1b,
    unsigned* __restrict__ w2b)
{
    __shared__ float xst[64][36];    // transposed x tile
    int tid = threadIdx.x;
    int t0 = blockIdx.x * 32;

    int token = tid >> 3, dseg = tid & 7;
    float4 xa = *(const float4*)(x + (size_t)(t0 + token) * D + dseg * 8);
    float4 xb = *(const float4*)(x + (size_t)(t0 + token) * D + dseg * 8 + 4);

    if (blockIdx.x < 16) {            // one-time bf16 fragment weight build
        int bi = blockIdx.x;
        if (tid < 128) {              // wob: 2048 u32 = [jt4][ks2][l64][e8]/2
            int i = bi * 128 + tid;
            int jt = i >> 9, ks = (i >> 8) & 1, l = (i >> 2) & 63, ee = 2 * (i & 3);
            int j = 16 * jt + (l & 15);
            int k = 32 * ks + 8 * (l >> 4) + ee;
            wob[i] = pack_bf2(wo[k * D + j], wo[(k + 1) * D + j]);
        }
#pragma unroll
        for (int e = 0; e < 2; ++e) { // w1b: 8192 u32 = [ft16][ks2][l64][e8]/2
            int i = bi * 512 + e * 256 + tid;
            int ft = i >> 9, ks = (i >> 8) & 1, l = (i >> 2) & 63, ee = 2 * (i & 3);
            int f = 16 * ft + (l & 15);
            int k = 32 * ks + 8 * (l >> 4) + ee;
            w1b[i] = pack_bf2(w1[k * F + f], w1[(k + 1) * F + f]);
        }
#pragma unroll
        for (int e = 0; e < 2; ++e) { // w2b: 8192 u32 = [jt4][ks8][l64][e8]/2
            int i = bi * 512 + e * 256 + tid;
            int jt = i >> 11, ks = (i >> 8) & 7, l = (i >> 2) & 63, ee = 2 * (i & 3);
            int j = 16 * jt + (l & 15);
            int k = 32 * ks + 8 * (l >> 4) + ee;
            w2b[i] = pack_bf2(w2[k * D + j], w2[(k + 1) * D + j]);
        }
    }

    xst[dseg * 8 + 0][token] = xa.x;
    xst[dseg * 8 + 1][token] = xa.y;
    xst[dseg * 8 + 2][token] = xa.z;
    xst[dseg * 8 + 3][token] = xa.w;
    xst[dseg * 8 + 4][token] = xb.x;
    xst[dseg * 8 + 5][token] = xb.y;
    xst[dseg * 8 + 6][token] = xb.z;
    xst[dseg * 8 + 7][token] = xb.w;
    __syncthreads();

    int j = tid & 63, g = tid >> 6;
    int h = j >> 4, k = j & 15;
    int wbase = h * (D * DH) + k;

    float qa[8], ka[8], va[8];
#pragma unroll
    for (int i = 0; i < 8; ++i) { qa[i] = bq[j]; ka[i] = bk[j]; va[i] = bv[j]; }

#pragma unroll 4
    for (int d = 0; d < D; ++d) {
        float wqv = wq[wbase + d * DH];
        float wkv = wk[wbase + d * DH];
        float wvv = wv[wbase + d * DH];
        float4 xv0 = *(const float4*)&xst[d][g * 8];
        float4 xv1 = *(const float4*)&xst[d][g * 8 + 4];
        float xe[8] = { xv0.x, xv0.y, xv0.z, xv0.w, xv1.x, xv1.y, xv1.z, xv1.w };
#pragma unroll
        for (int i = 0; i < 8; ++i) {
            qa[i] = fmaf(xe[i], wqv, qa[i]);
            ka[i] = fmaf(xe[i], wkv, ka[i]);
            va[i] = fmaf(xe[i], wvv, va[i]);
        }
    }
    int b = t0 >> 11;
    int pair = b * H + h;
    unsigned short vv[8];
#pragma unroll
    for (int i = 0; i < 8; ++i) {
        int t = t0 + g * 8 + i;
        int s = t & (S - 1);
        int off = (pair * S + s) * DH + k;
        Qb[off] = f2bf(qa[i] * (0.25f * LOG2E));
        Kb[off] = f2bf(ka[i]);
        vv[i] = f2bf(va[i]);
    }
    int s0 = (t0 & (S - 1)) + g * 8;
    uint4 pk;
    pk.x = (unsigned)vv[0] | ((unsigned)vv[1] << 16);
    pk.y = (unsigned)vv[2] | ((unsigned)vv[3] << 16);
    pk.z = (unsigned)vv[4] | ((unsigned)vv[5] << 16);
    pk.w = (unsigned)vv[6] | ((unsigned)vv[7] << 16);
    *(uint4*)(Vtg + (size_t)(pair * DH + k) * S + s0) = pk;
}

// ---------------------------------------------------------------- kernel 2
// MFMA flash attention partial (R18 verbatim, XCD-bijective swizzle).
__global__ __launch_bounds__(256) void k_attn_part(
    const unsigned short* __restrict__ Qb, const unsigned short* __restrict__ Kb,
    const unsigned short* __restrict__ Vtg, float* __restrict__ P)
{
    __shared__ unsigned short Kt[256][16];
    __shared__ unsigned short Vt[16][264];

    int tid = threadIdx.x, lane = tid & 63, w = tid >> 6;

    int bid0 = blockIdx.x;
    int z = (bid0 & 7) * 144 + (bid0 >> 3);
    int pair = z / CPP;
    int rem = z - pair * CPP;
    int qb = 0, cum = 0;
    while (cum + (qb >> 1) + 1 <= rem) { cum += (qb >> 1) + 1; ++qb; }
    int kc = rem - cum;
    int kbase = kc << 8;
    int qbase = qb << 7;

    {
        const uint4* src = (const uint4*)(Kb + (size_t)(pair * S + kbase + tid) * DH);
        uint4 lo = src[0], hi = src[1];
        *(uint4*)&Kt[tid][(tid & 1) * 8] = lo;
        *(uint4*)&Kt[tid][((tid & 1) ^ 1) * 8] = hi;
        int r = tid >> 4, cc = tid & 15;
        const uint4* vs = (const uint4*)(Vtg + (size_t)(pair * DH + r) * S + kbase + cc * 16);
        uint4 v0 = vs[0], v1 = vs[1];
        *(uint4*)&Vt[r][cc * 16] = v0;
        *(uint4*)&Vt[r][cc * 16 + 8] = v1;
    }
    __syncthreads();

    int qn = lane & 31, g = lane >> 5;
    int q0w = qbase + w * 32;
    int qg = q0w + qn;
    int vrow = lane & 15;

    s16x8 qf = *(const s16x8*)(Qb + (size_t)(pair * S + qg) * DH + g * 8);

    f32x16 czero;
#pragma unroll
    for (int i = 0; i < 16; ++i) czero[i] = 0.f;
    f32x16 acc = czero;
    float mrun = -1e30f, lsum = 0.f;

    int nt = ((q0w + 31 - kbase) >> 5) + 1;
    if (nt > 8) nt = 8;

    int krow0 = qn;
    s16x8 kf = *(const s16x8*)&Kt[krow0][(g ^ (krow0 & 1)) * 8];

    for (int t = 0; t < nt; ++t) {
        int kl = t * 32;
        s16x8 vf0 = *(const s16x8*)&Vt[vrow][kl + g * 8];
        s16x8 vf1 = *(const s16x8*)&Vt[vrow][kl + 16 + g * 8];
        int tn = (t + 1 < nt) ? (t + 1) : t;
        int krown = tn * 32 + qn;
        s16x8 kfn = *(const s16x8*)&Kt[krown][(g ^ (krown & 1)) * 8];

        f32x16 sc = __builtin_amdgcn_mfma_f32_32x32x16_bf16(kf, qf, czero, 0, 0, 0);
        if (t == nt - 1) {
            int qml = qg - (kbase + kl);
#pragma unroll
            for (int r = 0; r < 16; ++r) {
                int m = (r & 3) + 8 * (r >> 2) + 4 * g;
                sc[r] = (m <= qml) ? sc[r] : -1e30f;
            }
        }
        float t0a = fmaxf(fmaxf(sc[0], sc[1]), sc[2]);
        float t1a = fmaxf(fmaxf(sc[3], sc[4]), sc[5]);
        float t2a = fmaxf(fmaxf(sc[6], sc[7]), sc[8]);
        float t3a = fmaxf(fmaxf(sc[9], sc[10]), sc[11]);
        float t4a = fmaxf(fmaxf(sc[12], sc[13]), sc[14]);
        float tm = fmaxf(fmaxf(fmaxf(t0a, t1a), fmaxf(t2a, t3a)),
                         fmaxf(t4a, sc[15]));
        tm = fmaxf(tm, __shfl_xor(tm, 32, 64));
        float mnew = fmaxf(mrun, tm);
        float scale = exp2f(mrun - mnew);
        mrun = mnew;
        float p[16];
        float ts0 = 0.f, ts1 = 0.f, ts2 = 0.f, ts3 = 0.f;
#pragma unroll
        for (int r = 0; r < 16; r += 4) {
            p[r]     = exp2f(sc[r] - mnew);     ts0 += p[r];
            p[r + 1] = exp2f(sc[r + 1] - mnew); ts1 += p[r + 1];
            p[r + 2] = exp2f(sc[r + 2] - mnew); ts2 += p[r + 2];
            p[r + 3] = exp2f(sc[r + 3] - mnew); ts3 += p[r + 3];
        }
        float ts = (ts0 + ts1) + (ts2 + ts3);
        ts += __shfl_xor(ts, 32, 64);
        lsum = fmaf(lsum, scale, ts);
#pragma unroll
        for (int r = 0; r < 8; ++r) acc[r] *= scale;

        unsigned a0 = cvtpk(p[0],  p[1]);
        unsigned a1 = cvtpk(p[2],  p[3]);
        unsigned a2 = cvtpk(p[4],  p[5]);
        unsigned a3 = cvtpk(p[6],  p[7]);
        unsigned b0 = cvtpk(p[8],  p[9]);
        unsigned b1 = cvtpk(p[10], p[11]);
        unsigned b2 = cvtpk(p[12], p[13]);
        unsigned b3 = cvtpk(p[14], p[15]);
        plswap(a0, a2);
        plswap(a1, a3);
        plswap(b0, b2);
        plswap(b1, b3);
        union UU { unsigned u[4]; s16x8 v; };
        UU pf0, pf1;
        pf0.u[0] = a0; pf0.u[1] = a1; pf0.u[2] = a2; pf0.u[3] = a3;
        pf1.u[0] = b0; pf1.u[1] = b1; pf1.u[2] = b2; pf1.u[3] = b3;

        acc = __builtin_amdgcn_mfma_f32_32x32x16_bf16(vf0, pf0.v, acc, 0, 0, 0);
        acc = __builtin_amdgcn_mfma_f32_32x32x16_bf16(vf1, pf1.v, acc, 0, 0, 0);
        kf = kfn;
    }

    float* base = P + (size_t)z * PSTRIDE;
    if (lane < 32) {
        base[w * 32 + qn] = mrun;
        base[128 + w * 32 + qn] = lsum;
    }
    uint2 cA, cB;
    cA.x = pack_bf2(acc[0], acc[1]); cA.y = pack_bf2(acc[2], acc[3]);
    cB.x = pack_bf2(acc[4], acc[5]); cB.y = pack_bf2(acc[6], acc[7]);
    unsigned short* pa = (unsigned short*)(base + 256);
    *(uint2*)&pa[(w * 32 + qn) * 16 + 4 * g] = cA;
    *(uint2*)&pa[(w * 32 + qn) * 16 + 8 + 4 * g] = cB;
}

// ---------------------------------------------------------------- kernel 3
// MFMA post: merge + oproj(MFMA) + LN1 + FFN1(MFMA) + FFN2(MFMA) + LN2.
// 16 tokens / 256 threads / grid 512. mfma_f32_16x16x32_bf16 everywhere:
// A: lane l -> row l&15, k = 8*(l>>4)+e; C: col = lane&15, row = 4*(l>>4)+reg.
__global__ __launch_bounds__(256) void k_post(
    const float* __restrict__ P, const float* __restrict__ x,
    const unsigned* __restrict__ wob, const float* __restrict__ bo,
    const float* __restrict__ g1, const float* __restrict__ bb1,
    const unsigned* __restrict__ w1b, const float* __restrict__ b1,
    const unsigned* __restrict__ w2b, const float* __restrict__ b2,
    const float* __restrict__ g2, const float* __restrict__ bb2,
    float* __restrict__ out)
{
    __shared__ unsigned short Asb[16][72];   // merged attn out, bf16
    __shared__ float Os[16][68];             // oproj out / reused as Ys
    __shared__ float R1s[16][68];            // post-LN1 fp32 (residual 2)
    __shared__ unsigned short R1sb[16][72];  // post-LN1 bf16 (FFN1 A-op)
    __shared__ unsigned short Hhb[16][264];  // hidden, bf16

    int tid = threadIdx.x, lane = tid & 63, w = tid >> 6;
    int t0 = blockIdx.x * 16;
    int b = t0 >> 11;
    int sbase = t0 & (S - 1);
    int qb = sbase >> 7;
    int nc = (qb >> 1) + 1;
    int cum = 0;
#pragma unroll
    for (int i = 0; i < 16; ++i) cum += (i < qb) ? ((i >> 1) + 1) : 0;

    // ---- phase 1: merge split-K partials -> Asb (bf16)
    {
        int token = tid >> 4, sub = tid & 15;
        int h = sub >> 2, dq = sub & 3;          // 4 dims per thread
        int pair = b * H + h;
        int q = (sbase & 127) + token;
        const float* base0 = P + ((size_t)pair * CPP + cum) * PSTRIDE;

        float mv[8], sv[8]; uint2 uv[8];
#pragma unroll
        for (int c = 0; c < 8; ++c) {
            int cc = (c < nc) ? c : (nc - 1);
            const float* bc = base0 + cc * PSTRIDE;
            float m_ = bc[q];
            float s_ = bc[128 + q];
            uint2 u_ = *(const uint2*)((const unsigned*)(bc + 256) + q * 8 + dq * 2);
            bool valid = (c < nc);
            mv[c] = valid ? m_ : -1e30f;
            sv[c] = valid ? s_ : 0.f;
            uv[c].x = valid ? u_.x : 0u;
            uv[c].y = valid ? u_.y : 0u;
        }
        float M = fmaxf(fmaxf(fmaxf(mv[0], mv[1]), fmaxf(mv[2], mv[3])),
                        fmaxf(fmaxf(mv[4], mv[5]), fmaxf(mv[6], mv[7])));
        float Sm = 0.f, a0 = 0.f, a1 = 0.f, a2 = 0.f, a3 = 0.f;
#pragma unroll
        for (int c = 0; c < 8; ++c) {
            float e = exp2f(mv[c] - M);
            Sm = fmaf(sv[c], e, Sm);
            a0 = fmaf(__uint_as_float(uv[c].x << 16), e, a0);
            a1 = fmaf(__uint_as_float(uv[c].x & 0xffff0000u), e, a1);
            a2 = fmaf(__uint_as_float(uv[c].y << 16), e, a2);
            a3 = fmaf(__uint_as_float(uv[c].y & 0xffff0000u), e, a3);
        }
        float inv = 1.f / Sm;
        uint2 o;
        o.x = cvtpk(a0 * inv, a1 * inv);
        o.y = cvtpk(a2 * inv, a3 * inv);
        *(uint2*)&Asb[token][16 * h + 4 * dq] = o;
    }
    __syncthreads();

    // ---- phase 2: oproj MFMA (wave w = j-tile), + bias + residual -> Os
    {
        f32x4 c = {0.f, 0.f, 0.f, 0.f};
#pragma unroll
        for (int ks = 0; ks < 2; ++ks) {
            s16x8 af = *(const s16x8*)&Asb[lane & 15][32 * ks + 8 * (lane >> 4)];
            s16x8 bf = *(const s16x8*)(wob + (((w * 2) + ks) * 64 + lane) * 4);
            c = __builtin_amdgcn_mfma_f32_16x16x32_bf16(af, bf, c, 0, 0, 0);
        }
        int j = 16 * w + (lane & 15);
        int q4 = lane >> 4;
        float boj = bo[j];
#pragma unroll
        for (int r = 0; r < 4; ++r) {
            int tk = q4 * 4 + r;
            Os[tk][j] = c[r] + boj + x[(size_t)(t0 + tk) * D + j];
        }
    }
    __syncthreads();

    // ---- phase 3: LN1 -> R1s (fp32) + R1sb (bf16)
    {
        int j = lane;
        float gj = g1[j], bj = bb1[j];
#pragma unroll
        for (int i = 0; i < 4; ++i) {
            int tk = w * 4 + i;
            float o = Os[tk][j];
            float mu = wave_sum(o) * (1.f / 64.f);
            float dif = o - mu;
            float var = wave_sum(dif * dif) * (1.f / 64.f);
            float r1 = dif * rsqrtf(var + 1e-5f) * gj + bj;
            R1s[tk][j] = r1;
            R1sb[tk][j] = f2bf(r1);
        }
    }
    __syncthreads();

    // ---- phase 4: FFN1 MFMA (wave w -> f-tiles 4w..4w+3) + b1 + relu -> Hhb
    {
        int q4 = lane >> 4;
#pragma unroll
        for (int t = 0; t < 4; ++t) {
            int ft = w * 4 + t;
            f32x4 c = {0.f, 0.f, 0.f, 0.f};
#pragma unroll
            for (int ks = 0; ks < 2; ++ks) {
                s16x8 af = *(const s16x8*)&R1sb[lane & 15][32 * ks + 8 * (lane >> 4)];
                s16x8 bf = *(const s16x8*)(w1b + (((ft * 2) + ks) * 64 + lane) * 4);
                c = __builtin_amdgcn_mfma_f32_16x16x32_bf16(af, bf, c, 0, 0, 0);
            }
            int f = 16 * ft + (lane & 15);
            float b1f = b1[f];
#pragma unroll
            for (int r = 0; r < 4; ++r)
                Hhb[q4 * 4 + r][f] = f2bf(fmaxf(c[r] + b1f, 0.f));
        }
    }
    __syncthreads();

    // ---- phase 5: FFN2 MFMA (wave w = j-tile, 8 k-steps) + b2 + residual -> Ys
    {
        f32x4 c = {0.f, 0.f, 0.f, 0.f};
#pragma unroll
        for (int ks = 0; ks < 8; ++ks) {
            s16x8 af = *(const s16x8*)&Hhb[lane & 15][32 * ks + 8 * (lane >> 4)];
            s16x8 bf = *(const s16x8*)(w2b + (((w * 8) + ks) * 64 + lane) * 4);
            c = __builtin_amdgcn_mfma_f32_16x16x32_bf16(af, bf, c, 0, 0, 0);
        }
        int j = 16 * w + (lane & 15);
        int q4 = lane >> 4;
        float b2j = b2[j];
#pragma unroll
        for (int r = 0; r < 4; ++r) {
            int tk = q4 * 4 + r;
            Os[tk][j] = c[r] + b2j + R1s[tk][j];   // Os reused as Ys
        }
    }
    __syncthreads();

    // ---- phase 6: LN2 -> out
    {
        int j = lane;
        float gj = g2[j], bj = bb2[j];
#pragma unroll
        for (int i = 0; i < 4; ++i) {
            int tk = w * 4 + i;
            float y = Os[tk][j];
            float mu = wave_sum(y) * (1.f / 64.f);
            float dif = y - mu;
            float var = wave_sum(dif * dif) * (1.f / 64.f);
            out[(size_t)(t0 + tk) * D + j] = dif * rsqrtf(var + 1e-5f) * gj + bj;
        }
    }
}

// ----------------------------------------------------------------
extern "C" void kernel_launch(void* const* d_in, const int* in_sizes, int n_in,
                              void* d_out, int out_size, void* d_ws, size_t ws_size,
                              hipStream_t stream)
{
    const float* x   = (const float*)d_in[0];
    const float* wq  = (const float*)d_in[1];
    const float* bq  = (const float*)d_in[2];
    const float* wk  = (const float*)d_in[3];
    const float* bk  = (const float*)d_in[4];
    const float* wv  = (const float*)d_in[5];
    const float* bv  = (const float*)d_in[6];
    const float* wo  = (const float*)d_in[7];
    const float* bo  = (const float*)d_in[8];
    const float* g1  = (const float*)d_in[9];
    const float* be1 = (const float*)d_in[10];
    const float* w1  = (const float*)d_in[11];
    const float* b1  = (const float*)d_in[12];
    const float* w2  = (const float*)d_in[13];
    const float* b2  = (const float*)d_in[14];
    const float* g2  = (const float*)d_in[15];
    const float* be2 = (const float*)d_in[16];

    char* base = (char*)d_ws;
    unsigned short* Qb  = (unsigned short*)base;                  // 1 MB
    unsigned short* Kb  = (unsigned short*)(base + (1u << 20));   // 1 MB
    unsigned short* Vtg = (unsigned short*)(base + (2u << 20));   // 1 MB
    float*          P   = (float*)(base + (3u << 20));            // 5.9 MB
    unsigned*       wob = (unsigned*)(base + (9u << 20));         // 8 KB
    unsigned*       w1b = (unsigned*)(base + (9u << 20) + 0x10000); // 32 KB
    unsigned*       w2b = (unsigned*)(base + (9u << 20) + 0x20000); // 32 KB

    k_qkv      <<<T / 32, 256, 0, stream>>>(x, wq, bq, wk, bk, wv, bv,
                                            wo, w1, w2, Qb, Kb, Vtg,
                                            wob, w1b, w2b);
    k_attn_part<<<NZ, 256, 0, stream>>>(Qb, Kb, Vtg, P);
    k_post     <<<T / 16, 256, 0, stream>>>(P, x, wob, bo, g1, be1,
                                            w1b, b1, w2b, b2, g2, be2,
                                            (float*)d_out);
}

// Round 20
// 38.939 us; speedup vs baseline: 1.4656x; 1.1603x over previous
//
#include <hip/hip_runtime.h>

#define DEVFN __device__ __forceinline__

constexpr int B = 4, S = 2048, H = 4, DH = 16, D = 64, F = 256;
constexpr int T = B * S;        // 8192 tokens
constexpr int PAIRS = B * H;    // 16
constexpr int CPP = 72;         // chunk-blocks per pair = sum_{qb=0..15}(qb/2+1)
constexpr int NZ = PAIRS * CPP; // 1152 attention partial blocks
constexpr int PSTRIDE = 1280;   // floats: 128 m + 128 l + 128x16 bf16 acc
constexpr float LOG2E = 1.44269504f;

typedef __attribute__((ext_vector_type(8))) short s16x8;
typedef __attribute__((ext_vector_type(16))) float f32x16;
typedef __attribute__((ext_vector_type(4))) float f32x4;

DEVFN float wave_sum(float v) {
#pragma unroll
    for (int mask = 32; mask >= 1; mask >>= 1)
        v += __shfl_xor(v, mask, 64);
    return v;
}

DEVFN float bf2f(unsigned short u) { return __uint_as_float((unsigned)u << 16); }
DEVFN unsigned short f2bf(float f) {
    unsigned b = __float_as_uint(f);
    return (unsigned short)((b + 0x8000u) >> 16);
}
DEVFN unsigned pack_bf2(float lo, float hi) {
    unsigned a = __float_as_uint(lo), b = __float_as_uint(hi);
    return ((a + 0x8000u) >> 16) | ((b + 0x8000u) & 0xffff0000u);
}
DEVFN unsigned cvtpk(float lo, float hi) {
    unsigned r;
    asm("v_cvt_pk_bf16_f32 %0, %1, %2" : "=v"(r) : "v"(lo), "v"(hi));
    return r;
}
DEVFN void plswap(unsigned& a, unsigned& b) {
#if __has_builtin(__builtin_amdgcn_permlane32_swap)
    typedef unsigned uv2 __attribute__((ext_vector_type(2)));
    uv2 r = __builtin_amdgcn_permlane32_swap(a, b, false, false);
    a = r[0]; b = r[1];
#else
    asm volatile("v_permlane32_swap_b32 %0, %1" : "+v"(a), "+v"(b));
#endif
}

// ---------------------------------------------------------------- kernel 1
// MFMA QKV projection, 32 tokens per block (grid 256, 4 waves).
// x and wq/wk/wv staged as bf16 16x16x32 fragments in LDS
// (lane l: row/col = l&15, k = 8*(l>>4)+e — validated by R19).
// Blocks 0..15 also build k_post's fragment weights wob/w1b/w2b.
__global__ __launch_bounds__(256) void k_qkv(
    const float* __restrict__ x,
    const float* __restrict__ wq, const float* __restrict__ bq,
    const float* __restrict__ wk, const float* __restrict__ bk,
    const float* __restrict__ wv, const float* __restrict__ bv,
    const float* __restrict__ wo, const float* __restrict__ w1,
    const float* __restrict__ w2,
    unsigned short* __restrict__ Qb, unsigned short* __restrict__ Kb,
    unsigned short* __restrict__ Vtg,
    unsigned* __restrict__ wob, unsigned* __restrict__ w1b,
    unsigned* __restrict__ w2b)
{
    __shared__ __align__(16) unsigned short xfr[2][2][64][8];   // 4 KB
    __shared__ __align__(16) unsigned short wfr[12][2][64][8];  // 24 KB

    int tid = threadIdx.x, lane = tid & 63, w = tid >> 6;
    int t0 = blockIdx.x * 32;
    int b = t0 >> 11;
    int sbase = t0 & (S - 1);

    // ---- pack x fragments: 1024 u32, 4 per thread
#pragma unroll
    for (int e = 0; e < 4; ++e) {
        int i = e * 256 + tid;
        int tt = i >> 9, ks = (i >> 8) & 1, l = (i >> 2) & 63, ee = 2 * (i & 3);
        int token = 16 * tt + (l & 15);
        int kk = 32 * ks + 8 * (l >> 4) + ee;
        float2 xv = *(const float2*)(x + (size_t)(t0 + token) * D + kk);
        *(unsigned*)&xfr[tt][ks][l][ee] = pack_bf2(xv.x, xv.y);
    }
    // ---- pack QKV weight fragments: 6144 u32, 24 per thread
#pragma unroll
    for (int e = 0; e < 24; ++e) {
        int i = e * 256 + tid;
        int combo = i >> 9, ks = (i >> 8) & 1, l = (i >> 2) & 63, ee = 2 * (i & 3);
        int m = combo >> 2, jt = combo & 3;
        int j15 = l & 15;
        int kk = 32 * ks + 8 * (l >> 4) + ee;
        const float* wsrc = (m == 0) ? wq : (m == 1) ? wk : wv;
        float a = wsrc[jt * 1024 + kk * 16 + j15];
        float c = wsrc[jt * 1024 + (kk + 1) * 16 + j15];
        *(unsigned*)&wfr[combo][ks][l][ee] = pack_bf2(a, c);
    }

    if (blockIdx.x < 16) {            // one-time k_post fragment weight build
        int bi = blockIdx.x;
        if (tid < 128) {              // wob: 2048 u32
            int i = bi * 128 + tid;
            int jt = i >> 9, ks = (i >> 8) & 1, l = (i >> 2) & 63, ee = 2 * (i & 3);
            int j = 16 * jt + (l & 15);
            int k = 32 * ks + 8 * (l >> 4) + ee;
            wob[i] = pack_bf2(wo[k * D + j], wo[(k + 1) * D + j]);
        }
#pragma unroll
        for (int e = 0; e < 2; ++e) { // w1b: 8192 u32
            int i = bi * 512 + e * 256 + tid;
            int ft = i >> 9, ks = (i >> 8) & 1, l = (i >> 2) & 63, ee = 2 * (i & 3);
            int f = 16 * ft + (l & 15);
            int k = 32 * ks + 8 * (l >> 4) + ee;
            w1b[i] = pack_bf2(w1[k * F + f], w1[(k + 1) * F + f]);
        }
#pragma unroll
        for (int e = 0; e < 2; ++e) { // w2b: 8192 u32
            int i = bi * 512 + e * 256 + tid;
            int jt = i >> 11, ks = (i >> 8) & 7, l = (i >> 2) & 63, ee = 2 * (i & 3);
            int j = 16 * jt + (l & 15);
            int k = 32 * ks + 8 * (l >> 4) + ee;
            w2b[i] = pack_bf2(w2[k * D + j], w2[(k + 1) * D + j]);
        }
    }
    __syncthreads();

    // ---- MFMA: wave w handles combos 3w..3w+2 (combo = m*4+jt), tt = 0,1
    int j15 = lane & 15, q4 = lane >> 4;
#pragma unroll
    for (int t3 = 0; t3 < 3; ++t3) {
        int combo = w * 3 + t3;
        int m = combo >> 2, jt = combo & 3;
        int j = 16 * jt + j15;
        int pair = b * H + jt;
#pragma unroll
        for (int tt = 0; tt < 2; ++tt) {
            f32x4 c = {0.f, 0.f, 0.f, 0.f};
#pragma unroll
            for (int ks = 0; ks < 2; ++ks) {
                s16x8 af = *(const s16x8*)&xfr[tt][ks][lane][0];
                s16x8 bf = *(const s16x8*)&wfr[combo][ks][lane][0];
                c = __builtin_amdgcn_mfma_f32_16x16x32_bf16(af, bf, c, 0, 0, 0);
            }
            int s0 = sbase + 16 * tt + 4 * q4;
            if (m == 0) {
                float bj = bq[j];
#pragma unroll
                for (int r = 0; r < 4; ++r)
                    Qb[((size_t)pair * S + s0 + r) * DH + j15] =
                        f2bf((c[r] + bj) * (0.25f * LOG2E));
            } else if (m == 1) {
                float bj = bk[j];
#pragma unroll
                for (int r = 0; r < 4; ++r)
                    Kb[((size_t)pair * S + s0 + r) * DH + j15] = f2bf(c[r] + bj);
            } else {
                float bj = bv[j];
                uint2 o;
                o.x = pack_bf2(c[0] + bj, c[1] + bj);
                o.y = pack_bf2(c[2] + bj, c[3] + bj);
                *(uint2*)(Vtg + ((size_t)pair * DH + j15) * S + s0) = o;
            }
        }
    }
}

// ---------------------------------------------------------------- kernel 2
// MFMA flash attention partial (R18/R19 verbatim, XCD-bijective swizzle).
__global__ __launch_bounds__(256) void k_attn_part(
    const unsigned short* __restrict__ Qb, const unsigned short* __restrict__ Kb,
    const unsigned short* __restrict__ Vtg, float* __restrict__ P)
{
    __shared__ unsigned short Kt[256][16];
    __shared__ unsigned short Vt[16][264];

    int tid = threadIdx.x, lane = tid & 63, w = tid >> 6;

    int bid0 = blockIdx.x;
    int z = (bid0 & 7) * 144 + (bid0 >> 3);
    int pair = z / CPP;
    int rem = z - pair * CPP;
    int qb = 0, cum = 0;
    while (cum + (qb >> 1) + 1 <= rem) { cum += (qb >> 1) + 1; ++qb; }
    int kc = rem - cum;
    int kbase = kc << 8;
    int qbase = qb << 7;

    {
        const uint4* src = (const uint4*)(Kb + (size_t)(pair * S + kbase + tid) * DH);
        uint4 lo = src[0], hi = src[1];
        *(uint4*)&Kt[tid][(tid & 1) * 8] = lo;
        *(uint4*)&Kt[tid][((tid & 1) ^ 1) * 8] = hi;
        int r = tid >> 4, cc = tid & 15;
        const uint4* vs = (const uint4*)(Vtg + (size_t)(pair * DH + r) * S + kbase + cc * 16);
        uint4 v0 = vs[0], v1 = vs[1];
        *(uint4*)&Vt[r][cc * 16] = v0;
        *(uint4*)&Vt[r][cc * 16 + 8] = v1;
    }
    __syncthreads();

    int qn = lane & 31, g = lane >> 5;
    int q0w = qbase + w * 32;
    int qg = q0w + qn;
    int vrow = lane & 15;

    s16x8 qf = *(const s16x8*)(Qb + (size_t)(pair * S + qg) * DH + g * 8);

    f32x16 czero;
#pragma unroll
    for (int i = 0; i < 16; ++i) czero[i] = 0.f;
    f32x16 acc = czero;
    float mrun = -1e30f, lsum = 0.f;

    int nt = ((q0w + 31 - kbase) >> 5) + 1;
    if (nt > 8) nt = 8;

    int krow0 = qn;
    s16x8 kf = *(const s16x8*)&Kt[krow0][(g ^ (krow0 & 1)) * 8];

    for (int t = 0; t < nt; ++t) {
        int kl = t * 32;
        s16x8 vf0 = *(const s16x8*)&Vt[vrow][kl + g * 8];
        s16x8 vf1 = *(const s16x8*)&Vt[vrow][kl + 16 + g * 8];
        int tn = (t + 1 < nt) ? (t + 1) : t;
        int krown = tn * 32 + qn;
        s16x8 kfn = *(const s16x8*)&Kt[krown][(g ^ (krown & 1)) * 8];

        f32x16 sc = __builtin_amdgcn_mfma_f32_32x32x16_bf16(kf, qf, czero, 0, 0, 0);
        if (t == nt - 1) {
            int qml = qg - (kbase + kl);
#pragma unroll
            for (int r = 0; r < 16; ++r) {
                int m = (r & 3) + 8 * (r >> 2) + 4 * g;
                sc[r] = (m <= qml) ? sc[r] : -1e30f;
            }
        }
        float t0a = fmaxf(fmaxf(sc[0], sc[1]), sc[2]);
        float t1a = fmaxf(fmaxf(sc[3], sc[4]), sc[5]);
        float t2a = fmaxf(fmaxf(sc[6], sc[7]), sc[8]);
        float t3a = fmaxf(fmaxf(sc[9], sc[10]), sc[11]);
        float t4a = fmaxf(fmaxf(sc[12], sc[13]), sc[14]);
        float tm = fmaxf(fmaxf(fmaxf(t0a, t1a), fmaxf(t2a, t3a)),
                         fmaxf(t4a, sc[15]));
        tm = fmaxf(tm, __shfl_xor(tm, 32, 64));
        float mnew = fmaxf(mrun, tm);
        float scale = exp2f(mrun - mnew);
        mrun = mnew;
        float p[16];
        float ts0 = 0.f, ts1 = 0.f, ts2 = 0.f, ts3 = 0.f;
#pragma unroll
        for (int r = 0; r < 16; r += 4) {
            p[r]     = exp2f(sc[r] - mnew);     ts0 += p[r];
            p[r + 1] = exp2f(sc[r + 1] - mnew); ts1 += p[r + 1];
            p[r + 2] = exp2f(sc[r + 2] - mnew); ts2 += p[r + 2];
            p[r + 3] = exp2f(sc[r + 3] - mnew); ts3 += p[r + 3];
        }
        float ts = (ts0 + ts1) + (ts2 + ts3);
        ts += __shfl_xor(ts, 32, 64);
        lsum = fmaf(lsum, scale, ts);
#pragma unroll
        for (int r = 0; r < 8; ++r) acc[r] *= scale;

        unsigned a0 = cvtpk(p[0],  p[1]);
        unsigned a1 = cvtpk(p[2],  p[3]);
        unsigned a2 = cvtpk(p[4],  p[5]);
        unsigned a3 = cvtpk(p[6],  p[7]);
        unsigned b0 = cvtpk(p[8],  p[9]);
        unsigned b1 = cvtpk(p[10], p[11]);
        unsigned b2 = cvtpk(p[12], p[13]);
        unsigned b3 = cvtpk(p[14], p[15]);
        plswap(a0, a2);
        plswap(a1, a3);
        plswap(b0, b2);
        plswap(b1, b3);
        union UU { unsigned u[4]; s16x8 v; };
        UU pf0, pf1;
        pf0.u[0] = a0; pf0.u[1] = a1; pf0.u[2] = a2; pf0.u[3] = a3;
        pf1.u[0] = b0; pf1.u[1] = b1; pf1.u[2] = b2; pf1.u[3] = b3;

        acc = __builtin_amdgcn_mfma_f32_32x32x16_bf16(vf0, pf0.v, acc, 0, 0, 0);
        acc = __builtin_amdgcn_mfma_f32_32x32x16_bf16(vf1, pf1.v, acc, 0, 0, 0);
        kf = kfn;
    }

    float* base = P + (size_t)z * PSTRIDE;
    if (lane < 32) {
        base[w * 32 + qn] = mrun;
        base[128 + w * 32 + qn] = lsum;
    }
    uint2 cA, cB;
    cA.x = pack_bf2(acc[0], acc[1]); cA.y = pack_bf2(acc[2], acc[3]);
    cB.x = pack_bf2(acc[4], acc[5]); cB.y = pack_bf2(acc[6], acc[7]);
    unsigned short* pa = (unsigned short*)(base + 256);
    *(uint2*)&pa[(w * 32 + qn) * 16 + 4 * g] = cA;
    *(uint2*)&pa[(w * 32 + qn) * 16 + 8 + 4 * g] = cB;
}

// ---------------------------------------------------------------- kernel 3
// MFMA post (R19 verbatim): merge + oproj + LN1 + FFN1 + FFN2 + LN2.
__global__ __launch_bounds__(256) void k_post(
    const float* __restrict__ P, const float* __restrict__ x,
    const unsigned* __restrict__ wob, const float* __restrict__ bo,
    const float* __restrict__ g1, const float* __restrict__ bb1,
    const unsigned* __restrict__ w1b, const float* __restrict__ b1,
    const unsigned* __restrict__ w2b, const float* __restrict__ b2,
    const float* __restrict__ g2, const float* __restrict__ bb2,
    float* __restrict__ out)
{
    __shared__ unsigned short Asb[16][72];
    __shared__ float Os[16][68];
    __shared__ float R1s[16][68];
    __shared__ unsigned short R1sb[16][72];
    __shared__ unsigned short Hhb[16][264];

    int tid = threadIdx.x, lane = tid & 63, w = tid >> 6;
    int t0 = blockIdx.x * 16;
    int b = t0 >> 11;
    int sbase = t0 & (S - 1);
    int qb = sbase >> 7;
    int nc = (qb >> 1) + 1;
    int cum = 0;
#pragma unroll
    for (int i = 0; i < 16; ++i) cum += (i < qb) ? ((i >> 1) + 1) : 0;

    // ---- phase 1: merge split-K partials -> Asb (bf16)
    {
        int token = tid >> 4, sub = tid & 15;
        int h = sub >> 2, dq = sub & 3;
        int pair = b * H + h;
        int q = (sbase & 127) + token;
        const float* base0 = P + ((size_t)pair * CPP + cum) * PSTRIDE;

        float mv[8], sv[8]; uint2 uv[8];
#pragma unroll
        for (int c = 0; c < 8; ++c) {
            int cc = (c < nc) ? c : (nc - 1);
            const float* bc = base0 + cc * PSTRIDE;
            float m_ = bc[q];
            float s_ = bc[128 + q];
            uint2 u_ = *(const uint2*)((const unsigned*)(bc + 256) + q * 8 + dq * 2);
            bool valid = (c < nc);
            mv[c] = valid ? m_ : -1e30f;
            sv[c] = valid ? s_ : 0.f;
            uv[c].x = valid ? u_.x : 0u;
            uv[c].y = valid ? u_.y : 0u;
        }
        float M = fmaxf(fmaxf(fmaxf(mv[0], mv[1]), fmaxf(mv[2], mv[3])),
                        fmaxf(fmaxf(mv[4], mv[5]), fmaxf(mv[6], mv[7])));
        float Sm = 0.f, a0 = 0.f, a1 = 0.f, a2 = 0.f, a3 = 0.f;
#pragma unroll
        for (int c = 0; c < 8; ++c) {
            float e = exp2f(mv[c] - M);
            Sm = fmaf(sv[c], e, Sm);
            a0 = fmaf(__uint_as_float(uv[c].x << 16), e, a0);
            a1 = fmaf(__uint_as_float(uv[c].x & 0xffff0000u), e, a1);
            a2 = fmaf(__uint_as_float(uv[c].y << 16), e, a2);
            a3 = fmaf(__uint_as_float(uv[c].y & 0xffff0000u), e, a3);
        }
        float inv = 1.f / Sm;
        uint2 o;
        o.x = cvtpk(a0 * inv, a1 * inv);
        o.y = cvtpk(a2 * inv, a3 * inv);
        *(uint2*)&Asb[token][16 * h + 4 * dq] = o;
    }
    __syncthreads();

    // ---- phase 2: oproj MFMA + bias + residual -> Os
    {
        f32x4 c = {0.f, 0.f, 0.f, 0.f};
#pragma unroll
        for (int ks = 0; ks < 2; ++ks) {
            s16x8 af = *(const s16x8*)&Asb[lane & 15][32 * ks + 8 * (lane >> 4)];
            s16x8 bf = *(const s16x8*)(wob + (((w * 2) + ks) * 64 + lane) * 4);
            c = __builtin_amdgcn_mfma_f32_16x16x32_bf16(af, bf, c, 0, 0, 0);
        }
        int j = 16 * w + (lane & 15);
        int q4 = lane >> 4;
        float boj = bo[j];
#pragma unroll
        for (int r = 0; r < 4; ++r) {
            int tk = q4 * 4 + r;
            Os[tk][j] = c[r] + boj + x[(size_t)(t0 + tk) * D + j];
        }
    }
    __syncthreads();

    // ---- phase 3: LN1 -> R1s + R1sb
    {
        int j = lane;
        float gj = g1[j], bj = bb1[j];
#pragma unroll
        for (int i = 0; i < 4; ++i) {
            int tk = w * 4 + i;
            float o = Os[tk][j];
            float mu = wave_sum(o) * (1.f / 64.f);
            float dif = o - mu;
            float var = wave_sum(dif * dif) * (1.f / 64.f);
            float r1 = dif * rsqrtf(var + 1e-5f) * gj + bj;
            R1s[tk][j] = r1;
            R1sb[tk][j] = f2bf(r1);
        }
    }
    __syncthreads();

    // ---- phase 4: FFN1 MFMA + b1 + relu -> Hhb
    {
        int q4 = lane >> 4;
#pragma unroll
        for (int t = 0; t < 4; ++t) {
            int ft = w * 4 + t;
            f32x4 c = {0.f, 0.f, 0.f, 0.f};
#pragma unroll
            for (int ks = 0; ks < 2; ++ks) {
                s16x8 af = *(const s16x8*)&R1sb[lane & 15][32 * ks + 8 * (lane >> 4)];
                s16x8 bf = *(const s16x8*)(w1b + (((ft * 2) + ks) * 64 + lane) * 4);
                c = __builtin_amdgcn_mfma_f32_16x16x32_bf16(af, bf, c, 0, 0, 0);
            }
            int f = 16 * ft + (lane & 15);
            float b1f = b1[f];
#pragma unroll
            for (int r = 0; r < 4; ++r)
                Hhb[q4 * 4 + r][f] = f2bf(fmaxf(c[r] + b1f, 0.f));
        }
    }
    __syncthreads();

    // ---- phase 5: FFN2 MFMA + b2 + residual -> Ys (Os reused)
    {
        f32x4 c = {0.f, 0.f, 0.f, 0.f};
#pragma unroll
        for (int ks = 0; ks < 8; ++ks) {
            s16x8 af = *(const s16x8*)&Hhb[lane & 15][32 * ks + 8 * (lane >> 4)];
            s16x8 bf = *(const s16x8*)(w2b + (((w * 8) + ks) * 64 + lane) * 4);
            c = __builtin_amdgcn_mfma_f32_16x16x32_bf16(af, bf, c, 0, 0, 0);
        }
        int j = 16 * w + (lane & 15);
        int q4 = lane >> 4;
        float b2j = b2[j];
#pragma unroll
        for (int r = 0; r < 4; ++r) {
            int tk = q4 * 4 + r;
            Os[tk][j] = c[r] + b2j + R1s[tk][j];
        }
    }
    __syncthreads();

    // ---- phase 6: LN2 -> out
    {
        int j = lane;
        float gj = g2[j], bj = bb2[j];
#pragma unroll
        for (int i = 0; i < 4; ++i) {
            int tk = w * 4 + i;
            float y = Os[tk][j];
            float mu = wave_sum(y) * (1.f / 64.f);
            float dif = y - mu;
            float var = wave_sum(dif * dif) * (1.f / 64.f);
            out[(size_t)(t0 + tk) * D + j] = dif * rsqrtf(var + 1e-5f) * gj + bj;
        }
    }
}

// ----------------------------------------------------------------
extern "C" void kernel_launch(void* const* d_in, const int* in_sizes, int n_in,
                              void* d_out, int out_size, void* d_ws, size_t ws_size,
                              hipStream_t stream)
{
    const float* x   = (const float*)d_in[0];
    const float* wq  = (const float*)d_in[1];
    const float* bq  = (const float*)d_in[2];
    const float* wk  = (const float*)d_in[3];
    const float* bk  = (const float*)d_in[4];
    const float* wv  = (const float*)d_in[5];
    const float* bv  = (const float*)d_in[6];
    const float* wo  = (const float*)d_in[7];
    const float* bo  = (const float*)d_in[8];
    const float* g1  = (const float*)d_in[9];
    const float* be1 = (const float*)d_in[10];
    const float* w1  = (const float*)d_in[11];
    const float* b1  = (const float*)d_in[12];
    const float* w2  = (const float*)d_in[13];
    const float* b2  = (const float*)d_in[14];
    const float* g2  = (const float*)d_in[15];
    const float* be2 = (const float*)d_in[16];

    char* base = (char*)d_ws;
    unsigned short* Qb  = (unsigned short*)base;                  // 1 MB
    unsigned short* Kb  = (unsigned short*)(base + (1u << 20));   // 1 MB
    unsigned short* Vtg = (unsigned short*)(base + (2u << 20));   // 1 MB
    float*          P   = (float*)(base + (3u << 20));            // 5.9 MB
    unsigned*       wob = (unsigned*)(base + (9u << 20));         // 8 KB
    unsigned*       w1b = (unsigned*)(base + (9u << 20) + 0x10000); // 32 KB
    unsigned*       w2b = (unsigned*)(base + (9u << 20) + 0x20000); // 32 KB

    k_qkv      <<<T / 32, 256, 0, stream>>>(x, wq, bq, wk, bk, wv, bv,
                                            wo, w1, w2, Qb, Kb, Vtg,
                                            wob, w1b, w2b);
    k_attn_part<<<NZ, 256, 0, stream>>>(Qb, Kb, Vtg, P);
    k_post     <<<T / 16, 256, 0, stream>>>(P, x, wob, bo, g1, be1,
                                            w1b, b1, w2b, b2, g2, be2,
                                            (float*)d_out);
}

// Round 21
// 37.577 us; speedup vs baseline: 1.5187x; 1.0362x over previous
//
#include <hip/hip_runtime.h>

#define DEVFN __device__ __forceinline__

constexpr int B = 4, S = 2048, H = 4, DH = 16, D = 64, F = 256;
constexpr int T = B * S;        // 8192 tokens
constexpr int PAIRS = B * H;    // 16
constexpr int CPP = 72;         // chunk-blocks per pair = sum_{qb=0..15}(qb/2+1)
constexpr int NZ = PAIRS * CPP; // 1152 attention partial blocks
constexpr int PSTRIDE = 1280;   // floats: 128 m + 128 l + 128x16 bf16 acc
constexpr float LOG2E = 1.44269504f;

typedef __attribute__((ext_vector_type(8))) short s16x8;
typedef __attribute__((ext_vector_type(16))) float f32x16;
typedef __attribute__((ext_vector_type(4))) float f32x4;

DEVFN float wave_sum(float v) {
#pragma unroll
    for (int mask = 32; mask >= 1; mask >>= 1)
        v += __shfl_xor(v, mask, 64);
    return v;
}

DEVFN float bf2f(unsigned short u) { return __uint_as_float((unsigned)u << 16); }
DEVFN unsigned short f2bf(float f) {
    unsigned b = __float_as_uint(f);
    return (unsigned short)((b + 0x8000u) >> 16);
}
DEVFN unsigned pack_bf2(float lo, float hi) {
    unsigned a = __float_as_uint(lo), b = __float_as_uint(hi);
    return ((a + 0x8000u) >> 16) | ((b + 0x8000u) & 0xffff0000u);
}
DEVFN unsigned cvtpk(float lo, float hi) {
    unsigned r;
    asm("v_cvt_pk_bf16_f32 %0, %1, %2" : "=v"(r) : "v"(lo), "v"(hi));
    return r;
}
DEVFN void plswap(unsigned& a, unsigned& b) {
#if __has_builtin(__builtin_amdgcn_permlane32_swap)
    typedef unsigned uv2 __attribute__((ext_vector_type(2)));
    uv2 r = __builtin_amdgcn_permlane32_swap(a, b, false, false);
    a = r[0]; b = r[1];
#else
    asm volatile("v_permlane32_swap_b32 %0, %1" : "+v"(a), "+v"(b));
#endif
}

// ---------------------------------------------------------------- kernel 1
// MFMA QKV projection (R20 verbatim), 32 tokens per block.
__global__ __launch_bounds__(256) void k_qkv(
    const float* __restrict__ x,
    const float* __restrict__ wq, const float* __restrict__ bq,
    const float* __restrict__ wk, const float* __restrict__ bk,
    const float* __restrict__ wv, const float* __restrict__ bv,
    const float* __restrict__ wo, const float* __restrict__ w1,
    const float* __restrict__ w2,
    unsigned short* __restrict__ Qb, unsigned short* __restrict__ Kb,
    unsigned short* __restrict__ Vtg,
    unsigned* __restrict__ wob, unsigned* __restrict__ w1b,
    unsigned* __restrict__ w2b)
{
    __shared__ __align__(16) unsigned short xfr[2][2][64][8];   // 4 KB
    __shared__ __align__(16) unsigned short wfr[12][2][64][8];  // 24 KB

    int tid = threadIdx.x, lane = tid & 63, w = tid >> 6;
    int t0 = blockIdx.x * 32;
    int b = t0 >> 11;
    int sbase = t0 & (S - 1);

#pragma unroll
    for (int e = 0; e < 4; ++e) {
        int i = e * 256 + tid;
        int tt = i >> 9, ks = (i >> 8) & 1, l = (i >> 2) & 63, ee = 2 * (i & 3);
        int token = 16 * tt + (l & 15);
        int kk = 32 * ks + 8 * (l >> 4) + ee;
        float2 xv = *(const float2*)(x + (size_t)(t0 + token) * D + kk);
        *(unsigned*)&xfr[tt][ks][l][ee] = pack_bf2(xv.x, xv.y);
    }
#pragma unroll
    for (int e = 0; e < 24; ++e) {
        int i = e * 256 + tid;
        int combo = i >> 9, ks = (i >> 8) & 1, l = (i >> 2) & 63, ee = 2 * (i & 3);
        int m = combo >> 2, jt = combo & 3;
        int j15 = l & 15;
        int kk = 32 * ks + 8 * (l >> 4) + ee;
        const float* wsrc = (m == 0) ? wq : (m == 1) ? wk : wv;
        float a = wsrc[jt * 1024 + kk * 16 + j15];
        float c = wsrc[jt * 1024 + (kk + 1) * 16 + j15];
        *(unsigned*)&wfr[combo][ks][l][ee] = pack_bf2(a, c);
    }

    if (blockIdx.x < 16) {            // one-time k_post fragment weight build
        int bi = blockIdx.x;
        if (tid < 128) {
            int i = bi * 128 + tid;
            int jt = i >> 9, ks = (i >> 8) & 1, l = (i >> 2) & 63, ee = 2 * (i & 3);
            int j = 16 * jt + (l & 15);
            int k = 32 * ks + 8 * (l >> 4) + ee;
            wob[i] = pack_bf2(wo[k * D + j], wo[(k + 1) * D + j]);
        }
#pragma unroll
        for (int e = 0; e < 2; ++e) {
            int i = bi * 512 + e * 256 + tid;
            int ft = i >> 9, ks = (i >> 8) & 1, l = (i >> 2) & 63, ee = 2 * (i & 3);
            int f = 16 * ft + (l & 15);
            int k = 32 * ks + 8 * (l >> 4) + ee;
            w1b[i] = pack_bf2(w1[k * F + f], w1[(k + 1) * F + f]);
        }
#pragma unroll
        for (int e = 0; e < 2; ++e) {
            int i = bi * 512 + e * 256 + tid;
            int jt = i >> 11, ks = (i >> 8) & 7, l = (i >> 2) & 63, ee = 2 * (i & 3);
            int j = 16 * jt + (l & 15);
            int k = 32 * ks + 8 * (l >> 4) + ee;
            w2b[i] = pack_bf2(w2[k * D + j], w2[(k + 1) * D + j]);
        }
    }
    __syncthreads();

    int j15 = lane & 15, q4 = lane >> 4;
#pragma unroll
    for (int t3 = 0; t3 < 3; ++t3) {
        int combo = w * 3 + t3;
        int m = combo >> 2, jt = combo & 3;
        int j = 16 * jt + j15;
        int pair = b * H + jt;
#pragma unroll
        for (int tt = 0; tt < 2; ++tt) {
            f32x4 c = {0.f, 0.f, 0.f, 0.f};
#pragma unroll
            for (int ks = 0; ks < 2; ++ks) {
                s16x8 af = *(const s16x8*)&xfr[tt][ks][lane][0];
                s16x8 bf = *(const s16x8*)&wfr[combo][ks][lane][0];
                c = __builtin_amdgcn_mfma_f32_16x16x32_bf16(af, bf, c, 0, 0, 0);
            }
            int s0 = sbase + 16 * tt + 4 * q4;
            if (m == 0) {
                float bj = bq[j];
#pragma unroll
                for (int r = 0; r < 4; ++r)
                    Qb[((size_t)pair * S + s0 + r) * DH + j15] =
                        f2bf((c[r] + bj) * (0.25f * LOG2E));
            } else if (m == 1) {
                float bj = bk[j];
#pragma unroll
                for (int r = 0; r < 4; ++r)
                    Kb[((size_t)pair * S + s0 + r) * DH + j15] = f2bf(c[r] + bj);
            } else {
                float bj = bv[j];
                uint2 o;
                o.x = pack_bf2(c[0] + bj, c[1] + bj);
                o.y = pack_bf2(c[2] + bj, c[3] + bj);
                *(uint2*)(Vtg + ((size_t)pair * DH + j15) * S + s0) = o;
            }
        }
    }
}

// ---------------------------------------------------------------- kernel 2
// MFMA flash attention partial. 64-key super-tiles (one softmax reduction
// per 2 QK tiles) + deferred rescale (T13, THR=8 log2-domain): acc rescale
// skipped unless any lane's max grows >8 -> MFMA-to-MFMA accumulation chain.
__global__ __launch_bounds__(256) void k_attn_part(
    const unsigned short* __restrict__ Qb, const unsigned short* __restrict__ Kb,
    const unsigned short* __restrict__ Vtg, float* __restrict__ P)
{
    __shared__ unsigned short Kt[256][16];
    __shared__ unsigned short Vt[16][264];

    int tid = threadIdx.x, lane = tid & 63, w = tid >> 6;

    int bid0 = blockIdx.x;
    int z = (bid0 & 7) * 144 + (bid0 >> 3);  // XCD-bijective swizzle
    int pair = z / CPP;
    int rem = z - pair * CPP;
    int qb = 0, cum = 0;
    while (cum + (qb >> 1) + 1 <= rem) { cum += (qb >> 1) + 1; ++qb; }
    int kc = rem - cum;
    int kbase = kc << 8;
    int qbase = qb << 7;

    {
        const uint4* src = (const uint4*)(Kb + (size_t)(pair * S + kbase + tid) * DH);
        uint4 lo = src[0], hi = src[1];
        *(uint4*)&Kt[tid][(tid & 1) * 8] = lo;
        *(uint4*)&Kt[tid][((tid & 1) ^ 1) * 8] = hi;
        int r = tid >> 4, cc = tid & 15;
        const uint4* vs = (const uint4*)(Vtg + (size_t)(pair * DH + r) * S + kbase + cc * 16);
        uint4 v0 = vs[0], v1 = vs[1];
        *(uint4*)&Vt[r][cc * 16] = v0;
        *(uint4*)&Vt[r][cc * 16 + 8] = v1;
    }
    __syncthreads();

    int qn = lane & 31, g = lane >> 5;
    int q0w = qbase + w * 32;
    int qg = q0w + qn;
    int vrow = lane & 15;

    s16x8 qf = *(const s16x8*)(Qb + (size_t)(pair * S + qg) * DH + g * 8);

    f32x16 czero;
#pragma unroll
    for (int i = 0; i < 16; ++i) czero[i] = 0.f;
    f32x16 acc = czero;
    float mrun = -1e30f, lsum = 0.f;

    int nt = ((q0w + 31 - kbase) >> 5) + 1;
    if (nt > 8) nt = 8;
    int ntt = (nt + 1) >> 1;          // 64-key super-tiles

    for (int u = 0; u < ntt; ++u) {
        int kl = u * 64;
        int krowA = kl + qn, krowB = kl + 32 + qn;
        s16x8 kf0 = *(const s16x8*)&Kt[krowA][(g ^ (krowA & 1)) * 8];
        s16x8 kf1 = *(const s16x8*)&Kt[krowB][(g ^ (krowB & 1)) * 8];
        s16x8 vfa0 = *(const s16x8*)&Vt[vrow][kl + g * 8];
        s16x8 vfa1 = *(const s16x8*)&Vt[vrow][kl + 16 + g * 8];
        s16x8 vfb0 = *(const s16x8*)&Vt[vrow][kl + 32 + g * 8];
        s16x8 vfb1 = *(const s16x8*)&Vt[vrow][kl + 48 + g * 8];

        f32x16 sc0 = __builtin_amdgcn_mfma_f32_32x32x16_bf16(kf0, qf, czero, 0, 0, 0);
        f32x16 sc1 = __builtin_amdgcn_mfma_f32_32x32x16_bf16(kf1, qf, czero, 0, 0, 0);

        if (u == ntt - 1) {               // wave-uniform diagonal/tail mask
            int qml0 = qg - (kbase + kl);
            int qml1 = qml0 - 32;
#pragma unroll
            for (int r = 0; r < 16; ++r) {
                int m = (r & 3) + 8 * (r >> 2) + 4 * g;
                sc0[r] = (m <= qml0) ? sc0[r] : -1e30f;
                sc1[r] = (m <= qml1) ? sc1[r] : -1e30f;
            }
        }
        // max over 32 regs (pairwise + tree) + cross-half
        float mx[8];
#pragma unroll
        for (int r = 0; r < 8; ++r)
            mx[r] = fmaxf(fmaxf(sc0[r], sc0[r + 8]), fmaxf(sc1[r], sc1[r + 8]));
        float tm = fmaxf(fmaxf(fmaxf(mx[0], mx[1]), fmaxf(mx[2], mx[3])),
                         fmaxf(fmaxf(mx[4], mx[5]), fmaxf(mx[6], mx[7])));
        tm = fmaxf(tm, __shfl_xor(tm, 32, 64));

        if (__any(tm > mrun + 8.f)) {     // deferred rescale (T13)
            float mnew = fmaxf(mrun, tm);
            float scale = exp2f(mrun - mnew);
            mrun = mnew;
            lsum *= scale;
#pragma unroll
            for (int r = 0; r < 8; ++r) acc[r] *= scale;
        }
        // exp2 in place + sum
        float ts0 = 0.f, ts1 = 0.f, ts2 = 0.f, ts3 = 0.f;
#pragma unroll
        for (int r = 0; r < 16; r += 4) {
            sc0[r]     = exp2f(sc0[r] - mrun);     ts0 += sc0[r];
            sc0[r + 1] = exp2f(sc0[r + 1] - mrun); ts1 += sc0[r + 1];
            sc0[r + 2] = exp2f(sc0[r + 2] - mrun); ts2 += sc0[r + 2];
            sc0[r + 3] = exp2f(sc0[r + 3] - mrun); ts3 += sc0[r + 3];
        }
#pragma unroll
        for (int r = 0; r < 16; r += 4) {
            sc1[r]     = exp2f(sc1[r] - mrun);     ts0 += sc1[r];
            sc1[r + 1] = exp2f(sc1[r + 1] - mrun); ts1 += sc1[r + 1];
            sc1[r + 2] = exp2f(sc1[r + 2] - mrun); ts2 += sc1[r + 2];
            sc1[r + 3] = exp2f(sc1[r + 3] - mrun); ts3 += sc1[r + 3];
        }
        float ts = (ts0 + ts1) + (ts2 + ts3);
        ts += __shfl_xor(ts, 32, 64);
        lsum += ts;

        // pack P (both tiles) -> B-fragments via cvt_pk + permlane swap
        unsigned a0 = cvtpk(sc0[0],  sc0[1]);
        unsigned a1 = cvtpk(sc0[2],  sc0[3]);
        unsigned a2 = cvtpk(sc0[4],  sc0[5]);
        unsigned a3 = cvtpk(sc0[6],  sc0[7]);
        unsigned b0 = cvtpk(sc0[8],  sc0[9]);
        unsigned b1 = cvtpk(sc0[10], sc0[11]);
        unsigned b2 = cvtpk(sc0[12], sc0[13]);
        unsigned b3 = cvtpk(sc0[14], sc0[15]);
        plswap(a0, a2); plswap(a1, a3); plswap(b0, b2); plswap(b1, b3);
        unsigned c0 = cvtpk(sc1[0],  sc1[1]);
        unsigned c1 = cvtpk(sc1[2],  sc1[3]);
        unsigned c2 = cvtpk(sc1[4],  sc1[5]);
        unsigned c3 = cvtpk(sc1[6],  sc1[7]);
        unsigned d0 = cvtpk(sc1[8],  sc1[9]);
        unsigned d1 = cvtpk(sc1[10], sc1[11]);
        unsigned d2 = cvtpk(sc1[12], sc1[13]);
        unsigned d3 = cvtpk(sc1[14], sc1[15]);
        plswap(c0, c2); plswap(c1, c3); plswap(d0, d2); plswap(d1, d3);

        union UU { unsigned u[4]; s16x8 v; };
        UU pf0, pf1, pf2, pf3;
        pf0.u[0] = a0; pf0.u[1] = a1; pf0.u[2] = a2; pf0.u[3] = a3;
        pf1.u[0] = b0; pf1.u[1] = b1; pf1.u[2] = b2; pf1.u[3] = b3;
        pf2.u[0] = c0; pf2.u[1] = c1; pf2.u[2] = c2; pf2.u[3] = c3;
        pf3.u[0] = d0; pf3.u[1] = d1; pf3.u[2] = d2; pf3.u[3] = d3;

        acc = __builtin_amdgcn_mfma_f32_32x32x16_bf16(vfa0, pf0.v, acc, 0, 0, 0);
        acc = __builtin_amdgcn_mfma_f32_32x32x16_bf16(vfa1, pf1.v, acc, 0, 0, 0);
        acc = __builtin_amdgcn_mfma_f32_32x32x16_bf16(vfb0, pf2.v, acc, 0, 0, 0);
        acc = __builtin_amdgcn_mfma_f32_32x32x16_bf16(vfb1, pf3.v, acc, 0, 0, 0);
    }

    float* base = P + (size_t)z * PSTRIDE;
    if (lane < 32) {
        base[w * 32 + qn] = mrun;            // log2-domain max
        base[128 + w * 32 + qn] = lsum;
    }
    uint2 cA, cB;
    cA.x = pack_bf2(acc[0], acc[1]); cA.y = pack_bf2(acc[2], acc[3]);
    cB.x = pack_bf2(acc[4], acc[5]); cB.y = pack_bf2(acc[6], acc[7]);
    unsigned short* pa = (unsigned short*)(base + 256);
    *(uint2*)&pa[(w * 32 + qn) * 16 + 4 * g] = cA;
    *(uint2*)&pa[(w * 32 + qn) * 16 + 8 + 4 * g] = cB;
}

// ---------------------------------------------------------------- kernel 3
// MFMA post (R19/R20 verbatim): merge + oproj + LN1 + FFN1 + FFN2 + LN2.
__global__ __launch_bounds__(256) void k_post(
    const float* __restrict__ P, const float* __restrict__ x,
    const unsigned* __restrict__ wob, const float* __restrict__ bo,
    const float* __restrict__ g1, const float* __restrict__ bb1,
    const unsigned* __restrict__ w1b, const float* __restrict__ b1,
    const unsigned* __restrict__ w2b, const float* __restrict__ b2,
    const float* __restrict__ g2, const float* __restrict__ bb2,
    float* __restrict__ out)
{
    __shared__ unsigned short Asb[16][72];
    __shared__ float Os[16][68];
    __shared__ float R1s[16][68];
    __shared__ unsigned short R1sb[16][72];
    __shared__ unsigned short Hhb[16][264];

    int tid = threadIdx.x, lane = tid & 63, w = tid >> 6;
    int t0 = blockIdx.x * 16;
    int b = t0 >> 11;
    int sbase = t0 & (S - 1);
    int qb = sbase >> 7;
    int nc = (qb >> 1) + 1;
    int cum = 0;
#pragma unroll
    for (int i = 0; i < 16; ++i) cum += (i < qb) ? ((i >> 1) + 1) : 0;

    // ---- phase 1: merge split-K partials -> Asb (bf16)
    {
        int token = tid >> 4, sub = tid & 15;
        int h = sub >> 2, dq = sub & 3;
        int pair = b * H + h;
        int q = (sbase & 127) + token;
        const float* base0 = P + ((size_t)pair * CPP + cum) * PSTRIDE;

        float mv[8], sv[8]; uint2 uv[8];
#pragma unroll
        for (int c = 0; c < 8; ++c) {
            int cc = (c < nc) ? c : (nc - 1);
            const float* bc = base0 + cc * PSTRIDE;
            float m_ = bc[q];
            float s_ = bc[128 + q];
            uint2 u_ = *(const uint2*)((const unsigned*)(bc + 256) + q * 8 + dq * 2);
            bool valid = (c < nc);
            mv[c] = valid ? m_ : -1e30f;
            sv[c] = valid ? s_ : 0.f;
            uv[c].x = valid ? u_.x : 0u;
            uv[c].y = valid ? u_.y : 0u;
        }
        float M = fmaxf(fmaxf(fmaxf(mv[0], mv[1]), fmaxf(mv[2], mv[3])),
                        fmaxf(fmaxf(mv[4], mv[5]), fmaxf(mv[6], mv[7])));
        float Sm = 0.f, a0 = 0.f, a1 = 0.f, a2 = 0.f, a3 = 0.f;
#pragma unroll
        for (int c = 0; c < 8; ++c) {
            float e = exp2f(mv[c] - M);
            Sm = fmaf(sv[c], e, Sm);
            a0 = fmaf(__uint_as_float(uv[c].x << 16), e, a0);
            a1 = fmaf(__uint_as_float(uv[c].x & 0xffff0000u), e, a1);
            a2 = fmaf(__uint_as_float(uv[c].y << 16), e, a2);
            a3 = fmaf(__uint_as_float(uv[c].y & 0xffff0000u), e, a3);
        }
        float inv = 1.f / Sm;
        uint2 o;
        o.x = cvtpk(a0 * inv, a1 * inv);
        o.y = cvtpk(a2 * inv, a3 * inv);
        *(uint2*)&Asb[token][16 * h + 4 * dq] = o;
    }
    __syncthreads();

    // ---- phase 2: oproj MFMA + bias + residual -> Os
    {
        f32x4 c = {0.f, 0.f, 0.f, 0.f};
#pragma unroll
        for (int ks = 0; ks < 2; ++ks) {
            s16x8 af = *(const s16x8*)&Asb[lane & 15][32 * ks + 8 * (lane >> 4)];
            s16x8 bf = *(const s16x8*)(wob + (((w * 2) + ks) * 64 + lane) * 4);
            c = __builtin_amdgcn_mfma_f32_16x16x32_bf16(af, bf, c, 0, 0, 0);
        }
        int j = 16 * w + (lane & 15);
        int q4 = lane >> 4;
        float boj = bo[j];
#pragma unroll
        for (int r = 0; r < 4; ++r) {
            int tk = q4 * 4 + r;
            Os[tk][j] = c[r] + boj + x[(size_t)(t0 + tk) * D + j];
        }
    }
    __syncthreads();

    // ---- phase 3: LN1 -> R1s + R1sb
    {
        int j = lane;
        float gj = g1[j], bj = bb1[j];
#pragma unroll
        for (int i = 0; i < 4; ++i) {
            int tk = w * 4 + i;
            float o = Os[tk][j];
            float mu = wave_sum(o) * (1.f / 64.f);
            float dif = o - mu;
            float var = wave_sum(dif * dif) * (1.f / 64.f);
            float r1 = dif * rsqrtf(var + 1e-5f) * gj + bj;
            R1s[tk][j] = r1;
            R1sb[tk][j] = f2bf(r1);
        }
    }
    __syncthreads();

    // ---- phase 4: FFN1 MFMA + b1 + relu -> Hhb
    {
        int q4 = lane >> 4;
#pragma unroll
        for (int t = 0; t < 4; ++t) {
            int ft = w * 4 + t;
            f32x4 c = {0.f, 0.f, 0.f, 0.f};
#pragma unroll
            for (int ks = 0; ks < 2; ++ks) {
                s16x8 af = *(const s16x8*)&R1sb[lane & 15][32 * ks + 8 * (lane >> 4)];
                s16x8 bf = *(const s16x8*)(w1b + (((ft * 2) + ks) * 64 + lane) * 4);
                c = __builtin_amdgcn_mfma_f32_16x16x32_bf16(af, bf, c, 0, 0, 0);
            }
            int f = 16 * ft + (lane & 15);
            float b1f = b1[f];
#pragma unroll
            for (int r = 0; r < 4; ++r)
                Hhb[q4 * 4 + r][f] = f2bf(fmaxf(c[r] + b1f, 0.f));
        }
    }
    __syncthreads();

    // ---- phase 5: FFN2 MFMA + b2 + residual -> Ys (Os reused)
    {
        f32x4 c = {0.f, 0.f, 0.f, 0.f};
#pragma unroll
        for (int ks = 0; ks < 8; ++ks) {
            s16x8 af = *(const s16x8*)&Hhb[lane & 15][32 * ks + 8 * (lane >> 4)];
            s16x8 bf = *(const s16x8*)(w2b + (((w * 8) + ks) * 64 + lane) * 4);
            c = __builtin_amdgcn_mfma_f32_16x16x32_bf16(af, bf, c, 0, 0, 0);
        }
        int j = 16 * w + (lane & 15);
        int q4 = lane >> 4;
        float b2j = b2[j];
#pragma unroll
        for (int r = 0; r < 4; ++r) {
            int tk = q4 * 4 + r;
            Os[tk][j] = c[r] + b2j + R1s[tk][j];
        }
    }
    __syncthreads();

    // ---- phase 6: LN2 -> out
    {
        int j = lane;
        float gj = g2[j], bj = bb2[j];
#pragma unroll
        for (int i = 0; i < 4; ++i) {
            int tk = w * 4 + i;
            float y = Os[tk][j];
            float mu = wave_sum(y) * (1.f / 64.f);
            float dif = y - mu;
            float var = wave_sum(dif * dif) * (1.f / 64.f);
            out[(size_t)(t0 + tk) * D + j] = dif * rsqrtf(var + 1e-5f) * gj + bj;
        }
    }
}

// ----------------------------------------------------------------
extern "C" void kernel_launch(void* const* d_in, const int* in_sizes, int n_in,
                              void* d_out, int out_size, void* d_ws, size_t ws_size,
                              hipStream_t stream)
{
    const float* x   = (const float*)d_in[0];
    const float* wq  = (const float*)d_in[1];
    const float* bq  = (const float*)d_in[2];
    const float* wk  = (const float*)d_in[3];
    const float* bk  = (const float*)d_in[4];
    const float* wv  = (const float*)d_in[5];
    const float* bv  = (const float*)d_in[6];
    const float* wo  = (const float*)d_in[7];
    const float* bo  = (const float*)d_in[8];
    const float* g1  = (const float*)d_in[9];
    const float* be1 = (const float*)d_in[10];
    const float* w1  = (const float*)d_in[11];
    const float* b1  = (const float*)d_in[12];
    const float* w2  = (const float*)d_in[13];
    const float* b2  = (const float*)d_in[14];
    const float* g2  = (const float*)d_in[15];
    const float* be2 = (const float*)d_in[16];

    char* base = (char*)d_ws;
    unsigned short* Qb  = (unsigned short*)base;                  // 1 MB
    unsigned short* Kb  = (unsigned short*)(base + (1u << 20));   // 1 MB
    unsigned short* Vtg = (unsigned short*)(base + (2u << 20));   // 1 MB
    float*          P   = (float*)(base + (3u << 20));            // 5.9 MB
    unsigned*       wob = (unsigned*)(base + (9u << 20));         // 8 KB
    unsigned*       w1b = (unsigned*)(base + (9u << 20) + 0x10000); // 32 KB
    unsigned*       w2b = (unsigned*)(base + (9u << 20) + 0x20000); // 32 KB

    k_qkv      <<<T / 32, 256, 0, stream>>>(x, wq, bq, wk, bk, wv, bv,
                                            wo, w1, w2, Qb, Kb, Vtg,
                                            wob, w1b, w2b);
    k_attn_part<<<NZ, 256, 0, stream>>>(Qb, Kb, Vtg, P);
    k_post     <<<T / 16, 256, 0, stream>>>(P, x, wob, bo, g1, be1,
                                            w1b, b1, w2b, b2, g2, be2,
                                            (float*)d_out);
}